// Round 5
// baseline (4415.646 us; speedup 1.0000x reference)
//
#include <hip/hip_runtime.h>

#define S_LEN 8192
#define NH 16
#define NV 4
#define NB 512

#define NL  (-1.44269504088896340736f)   // -log2(e)
#define S2L (-2.88539008177792681472f)   // -2*log2(e)

typedef float v2f __attribute__((ext_vector_type(2)));

// ---------- DPP helpers ----------
template<int R>
__device__ __forceinline__ float rotf(float v) {
    return __int_as_float(__builtin_amdgcn_mov_dpp(__float_as_int(v), 0x120 + R, 0xF, 0xF, true));
}
__device__ __forceinline__ float qxor1(float v) {  // quad_perm [1,0,3,2]
    return __int_as_float(__builtin_amdgcn_mov_dpp(__float_as_int(v), 0xB1, 0xF, 0xF, true));
}
__device__ __forceinline__ float qxor2(float v) {  // quad_perm [2,3,0,1]
    return __int_as_float(__builtin_amdgcn_mov_dpp(__float_as_int(v), 0x4E, 0xF, 0xF, true));
}
__device__ __forceinline__ float qrev(float v) {   // quad_perm [3,2,1,0] == xor 3
    return __int_as_float(__builtin_amdgcn_mov_dpp(__float_as_int(v), 0x1B, 0xF, 0xF, true));
}

__device__ __forceinline__ float frcp(float x) { return __builtin_amdgcn_rcpf(x); }
__device__ __forceinline__ float4 ld4(const float* p) { return *(const float4*)p; }

// hp[k] = { h[(j+sgn*2k)&15], h[(j+sgn*(2k+1))&15] }
#define FILL_HP(hp, h)                                   \
    do {                                                 \
        hp[0].x = (h);        hp[0].y = rotf<1>(h);      \
        hp[1].x = rotf<2>(h); hp[1].y = rotf<3>(h);      \
        hp[2].x = rotf<4>(h); hp[2].y = rotf<5>(h);      \
        hp[3].x = rotf<6>(h); hp[3].y = rotf<7>(h);      \
        hp[4].x = rotf<8>(h); hp[4].y = rotf<9>(h);      \
        hp[5].x = rotf<10>(h); hp[5].y = rotf<11>(h);    \
        hp[6].x = rotf<12>(h); hp[6].y = rotf<13>(h);    \
        hp[7].x = rotf<14>(h); hp[7].y = rotf<15>(h);    \
    } while (0)

// 16-dot, depth 5 from hp-ready: 2+2 fma chains + pk-add tree + hadd.
__device__ __forceinline__ float dot8p(const v2f* __restrict__ w, const v2f* hp, float start) {
    v2f c0 = __builtin_elementwise_fma(w[0], hp[0], (v2f){start, 0.0f});
    c0 = __builtin_elementwise_fma(w[1], hp[1], c0);
    v2f c1 = __builtin_elementwise_fma(w[3], hp[3], w[2] * hp[2]);
    v2f c2 = __builtin_elementwise_fma(w[5], hp[5], w[4] * hp[4]);
    v2f c3 = __builtin_elementwise_fma(w[7], hp[7], w[6] * hp[6]);
    v2f s = (c0 + c1) + (c2 + c3);
    return s.x + s.y;
}

// 128 blocks x 64 threads. Each wave: 4 batch elements x 16 lanes.
__global__ __launch_bounds__(64, 1) void rnn_kernel(
    const float* __restrict__ gt,
    const float* __restrict__ eWih, const float* __restrict__ eWhh,
    const float* __restrict__ ebih, const float* __restrict__ ebhh,
    const float* __restrict__ dWih, const float* __restrict__ dWhh,
    const float* __restrict__ dbih, const float* __restrict__ dbhh,
    const float* __restrict__ oW,  const float* __restrict__ ob,
    float* __restrict__ outs)                 // [NB][NV][S_LEN] logit scratch
{
    const int lane = threadIdx.x;
    const int j    = lane & 15;
    const int q    = j & 3;
    const int b    = blockIdx.x * 4 + (lane >> 4);

    // DPP row_ror direction probe (direction-agnostic weight indexing).
    int probe = __builtin_amdgcn_mov_dpp(j, 0x121, 0xF, 0xF, true);
    const int sgn = (probe == ((j + 1) & 15)) ? 1 : -1;

    const float* gb = gt + (size_t)b * (NV * S_LEN);

    // ---------------- encoder weights (paired, rotated, exp2-prescaled) ----------------
    v2f ewr[8], ewz[8], ewn[8];
#pragma unroll
    for (int p = 0; p < 8; ++p) {
        int k0 = (j + sgn * (2 * p)) & 15;
        int k1 = (j + sgn * (2 * p + 1)) & 15;
        ewr[p] = (v2f){NL * eWhh[(0 * NH + j) * NH + k0], NL * eWhh[(0 * NH + j) * NH + k1]};
        ewz[p] = (v2f){NL * eWhh[(1 * NH + j) * NH + k0], NL * eWhh[(1 * NH + j) * NH + k1]};
        ewn[p] = (v2f){S2L * eWhh[(2 * NH + j) * NH + k0], S2L * eWhh[(2 * NH + j) * NH + k1]};
    }
    float exr[NV], exz[NV], exn[NV];
#pragma unroll
    for (int v = 0; v < NV; ++v) {
        exr[v] = NL  * eWih[(0 * NH + j) * NV + v];
        exz[v] = NL  * eWih[(1 * NH + j) * NV + v];
        exn[v] = S2L * eWih[(2 * NH + j) * NV + v];
    }
    const float c_er  = NL  * (ebih[j] + ebhh[j]);
    const float c_ez  = NL  * (ebih[NH + j] + ebhh[NH + j]);
    const float c_ein = S2L * ebih[2 * NH + j];
    const float c_ehn = S2L * ebhh[2 * NH + j];

    float h = 0.0f;

    // estep: gate args pre-scaled so they feed exp2 directly.
    auto estep = [&](float x0, float x1, float x2, float x3) {
        float xr = fmaf(exr[0], x0, fmaf(exr[1], x1, fmaf(exr[2], x2, fmaf(exr[3], x3, c_er))));
        float xz = fmaf(exz[0], x0, fmaf(exz[1], x1, fmaf(exz[2], x2, fmaf(exz[3], x3, c_ez))));
        float xn = fmaf(exn[0], x0, fmaf(exn[1], x1, fmaf(exn[2], x2, fmaf(exn[3], x3, c_ein))));
        v2f hp[8];
        FILL_HP(hp, h);
        float ar = dot8p(ewr, hp, xr);       // = -log2e * (raw r pre-act)
        float az = dot8p(ewz, hp, xz);
        float hn = dot8p(ewn, hp, c_ehn);    // = -2log2e * (hn dot + bhh_n)
        float r  = frcp(1.0f + exp2f(ar));
        float z  = frcp(1.0f + exp2f(az));
        float t2 = fmaf(-2.0f, z, 2.0f);     // z-side, parallel to r-chain
        float tb = fmaf(z, h, z - 1.0f);
        float y  = fmaf(r, hn, xn);          // -2log2e * tanh-arg
        float w2 = frcp(1.0f + exp2f(y));
        h = fmaf(w2, t2, tb);
    };

    // ---------------- encoder loop ----------------
    {
        float4 A0 = ld4(gb + 0 * S_LEN), A1 = ld4(gb + 1 * S_LEN),
               A2 = ld4(gb + 2 * S_LEN), A3 = ld4(gb + 3 * S_LEN);
        float4 B0 = ld4(gb + 0 * S_LEN + 4), B1 = ld4(gb + 1 * S_LEN + 4),
               B2 = ld4(gb + 2 * S_LEN + 4), B3 = ld4(gb + 3 * S_LEN + 4);
        for (int t = 0; t < S_LEN; t += 8) {
            estep(A0.x, A1.x, A2.x, A3.x);
            estep(A0.y, A1.y, A2.y, A3.y);
            estep(A0.z, A1.z, A2.z, A3.z);
            estep(A0.w, A1.w, A2.w, A3.w);
            int ta = t + 8;  if (ta > S_LEN - 4) ta = S_LEN - 4;
            A0 = ld4(gb + 0 * S_LEN + ta); A1 = ld4(gb + 1 * S_LEN + ta);
            A2 = ld4(gb + 2 * S_LEN + ta); A3 = ld4(gb + 3 * S_LEN + ta);
            estep(B0.x, B1.x, B2.x, B3.x);
            estep(B0.y, B1.y, B2.y, B3.y);
            estep(B0.z, B1.z, B2.z, B3.z);
            estep(B0.w, B1.w, B2.w, B3.w);
            int tb2 = t + 12; if (tb2 > S_LEN - 4) tb2 = S_LEN - 4;
            B0 = ld4(gb + 0 * S_LEN + tb2); B1 = ld4(gb + 1 * S_LEN + tb2);
            B2 = ld4(gb + 2 * S_LEN + tb2); B3 = ld4(gb + 3 * S_LEN + tb2);
        }
    }

    // ---------------- decoder weights ----------------
    v2f dwr[8], dwz[8], dwn[8], ow2[8];
#pragma unroll
    for (int p = 0; p < 8; ++p) {
        int k0 = (j + sgn * (2 * p)) & 15;
        int k1 = (j + sgn * (2 * p + 1)) & 15;
        dwr[p] = (v2f){NL * dWhh[(0 * NH + j) * NH + k0], NL * dWhh[(0 * NH + j) * NH + k1]};
        dwz[p] = (v2f){NL * dWhh[(1 * NH + j) * NH + k0], NL * dWhh[(1 * NH + j) * NH + k1]};
        dwn[p] = (v2f){S2L * dWhh[(2 * NH + j) * NH + k0], S2L * dWhh[(2 * NH + j) * NH + k1]};
        ow2[p] = (v2f){oW[q * NH + k0], oW[q * NH + k1]};
    }
    const float sR  = NL  * (dbih[j] + dbhh[j]);             // r-dot start
    const float sZ  = NL  * (dbih[NH + j] + dbhh[NH + j]);   // z-dot start
    const float sHn = S2L * dbhh[2 * NH + j];                // hn-dot start
    const float cIn = S2L * dbih[2 * NH + j];                // inn bias (n-path const)
    // Multiplicative one-hot constants 2^{scaled K}, REGISTER order m (class = m ^ q):
    float EKr[NV], EKz[NV], EKn[NV];
#pragma unroll
    for (int m = 0; m < NV; ++m) {
        int c = m ^ q;
        EKr[m] = exp2f(NL  * dWih[(0 * NH + j) * NV + c]);
        EKz[m] = exp2f(NL  * dWih[(1 * NH + j) * NV + c]);
        EKn[m] = exp2f(S2L * dWih[(2 * NH + j) * NV + c]);
    }
    const float obq = ob[q];

    // dstep: gathers h'(t-1); dots; exp2 of gate args overlaps the argmax tournament;
    // gate = rcp(fma(E, EK_class, 1)). Returns logits of step t-1 (lane's class q).
    auto dstep = [&]() -> float {
        v2f hp[8];
        FILL_HP(hp, h);
        float ar = dot8p(dwr, hp, sR);
        float az = dot8p(dwz, hp, sZ);
        float hn = dot8p(dwn, hp, sHn);
        float oa = dot8p(ow2, hp, obq);
        float o_b = qxor1(oa);               // out[q^1]
        float o_c = qxor2(oa);               // out[q^2]
        float o_d = qrev(oa);                // out[q^3]
        bool cA = o_b > oa;  float mA = fmaxf(oa, o_b);
        bool cB = o_d > o_c; float mB = fmaxf(o_c, o_d);
        bool hi = mB > mA;
        float ekr = hi ? (cB ? EKr[3] : EKr[2]) : (cA ? EKr[1] : EKr[0]);
        float ekz = hi ? (cB ? EKz[3] : EKz[2]) : (cA ? EKz[1] : EKz[0]);
        float ekn = hi ? (cB ? EKn[3] : EKn[2]) : (cA ? EKn[1] : EKn[0]);
        float r  = frcp(fmaf(exp2f(ar), ekr, 1.0f));
        float z  = frcp(fmaf(exp2f(az), ekz, 1.0f));
        float t2 = fmaf(-2.0f, z, 2.0f);
        float tb = fmaf(z, h, z - 1.0f);
        float y  = fmaf(r, hn, cIn);
        float w2 = frcp(fmaf(exp2f(y), ekn, 1.0f));
        h = fmaf(w2, t2, tb);
        return oa;
    };

    float* op = outs + ((size_t)(b * NV + q) << 13);   // this lane's class stream
    const bool storer = (j < 4);

    // t = 0: x0 = zeros (EK factors = 1), no previous logits
    {
        v2f hp[8];
        FILL_HP(hp, h);
        float ar = dot8p(dwr, hp, sR);
        float az = dot8p(dwz, hp, sZ);
        float hn = dot8p(dwn, hp, sHn);
        float r  = frcp(1.0f + exp2f(ar));
        float z  = frcp(1.0f + exp2f(az));
        float t2 = fmaf(-2.0f, z, 2.0f);
        float tb = fmaf(z, h, z - 1.0f);
        float y  = fmaf(r, hn, cIn);
        float w2 = frcp(1.0f + exp2f(y));
        h = fmaf(w2, t2, tb);
    }
    // t = 1..8188: 2047 groups of 4, one float4 logit store per group
    for (int u = 0; u < 2047; ++u) {
        float4 o4;
        o4.x = dstep();
        o4.y = dstep();
        o4.z = dstep();
        o4.w = dstep();
        if (storer) *(float4*)(op + 4 * u) = o4;
    }
    // t = 8189..8191 + final-step logits
    {
        float4 o4;
        o4.x = dstep();
        o4.y = dstep();
        o4.z = dstep();
        v2f hp[8];
        FILL_HP(hp, h);
        o4.w = dot8p(ow2, hp, obq);
        if (storer) *(float4*)(op + 4 * 2047) = o4;
    }
}

// Epilogue: NLL over all (b,t) from stored logits + gt targets; zero the scratch
// via the SAME addresses each thread read (no cross-thread race).
__global__ __launch_bounds__(1024) void loss_kernel(
    const float* __restrict__ gt, float* __restrict__ outs, float* __restrict__ loss)
{
    int tid = blockIdx.x * 1024 + threadIdx.x;   // over NB*S_LEN
    int t = tid & (S_LEN - 1);
    int b = tid >> 13;
    float* os = outs + ((size_t)(b * NV) << 13) + t;
    float o0 = os[0], o1 = os[1 << 13], o2 = os[2 << 13], o3 = os[3 << 13];
    const float* g = gt + (size_t)b * (NV * S_LEN) + t;
    float p0 = g[0], p1 = g[S_LEN], p2 = g[2 * S_LEN], p3 = g[3 * S_LEN];
    int tg = (p1 > p0) ? 1 : 0;  float bm = fmaxf(p0, p1);
    tg = (p2 > bm) ? 2 : tg;     bm = fmaxf(p2, bm);
    tg = (p3 > bm) ? 3 : tg;
    float vt = (tg & 1) ? ((tg & 2) ? o3 : o1) : ((tg & 2) ? o2 : o0);
    float mx = fmaxf(fmaxf(o0, o1), fmaxf(o2, o3));
    float ss = __expf(o0 - mx) + __expf(o1 - mx) + __expf(o2 - mx) + __expf(o3 - mx);
    float v  = (mx - vt) + __logf(ss);
    os[0] = 0.f; os[1 << 13] = 0.f; os[2 << 13] = 0.f; os[3 << 13] = 0.f;
    // wave reduce
#pragma unroll
    for (int d = 1; d < 64; d <<= 1) v += __shfl_xor(v, d, 64);
    __shared__ float sm[16];
    int w = threadIdx.x >> 6;
    if ((threadIdx.x & 63) == 0) sm[w] = v;
    __syncthreads();
    if (threadIdx.x < 16) {
        float s = sm[threadIdx.x];
#pragma unroll
        for (int d = 1; d < 16; d <<= 1) s += __shfl_xor(s, d, 64);
        if (threadIdx.x == 0) atomicAdd(loss, s * (1.0f / NB));
    }
}

extern "C" void kernel_launch(void* const* d_in, const int* in_sizes, int n_in,
                              void* d_out, int out_size, void* d_ws, size_t ws_size,
                              hipStream_t stream) {
    (void)in_sizes; (void)n_in; (void)d_ws; (void)ws_size; (void)out_size;
    const float* gt   = (const float*)d_in[0];
    const float* eWih = (const float*)d_in[1];
    const float* eWhh = (const float*)d_in[2];
    const float* ebih = (const float*)d_in[3];
    const float* ebhh = (const float*)d_in[4];
    const float* dWih = (const float*)d_in[5];
    const float* dWhh = (const float*)d_in[6];
    const float* dbih = (const float*)d_in[7];
    const float* dbhh = (const float*)d_in[8];
    const float* oW   = (const float*)d_in[9];
    const float* ob   = (const float*)d_in[10];

    float* out  = (float*)d_out;       // out[0] = loss
    float* outs = out + 1;             // [NB][NV][S_LEN] logit scratch == output_batch region
    hipMemsetAsync(d_out, 0, sizeof(float), stream);   // zero loss only
    rnn_kernel<<<NB / 4, 64, 0, stream>>>(gt, eWih, eWhh, ebih, ebhh,
                                          dWih, dWhh, dbih, dbhh, oW, ob, outs);
    loss_kernel<<<(NB * S_LEN) / 1024, 1024, 0, stream>>>(gt, outs, out);
}

// Round 6
// 4043.700 us; speedup vs baseline: 1.0920x; 1.0920x over previous
//
#include <hip/hip_runtime.h>

#define S_LEN 8192
#define NH 16
#define NV 4
#define NB 512

#define NL  (-1.44269504088896340736f)   // -log2(e)
#define S2L (-2.88539008177792681472f)   // -2*log2(e)

typedef float v2f __attribute__((ext_vector_type(2)));

// ---------- DPP helpers ----------
template<int R>
__device__ __forceinline__ float rotf(float v) {
    return __int_as_float(__builtin_amdgcn_mov_dpp(__float_as_int(v), 0x120 + R, 0xF, 0xF, true));
}
__device__ __forceinline__ float qxor1(float v) {  // quad_perm [1,0,3,2]
    return __int_as_float(__builtin_amdgcn_mov_dpp(__float_as_int(v), 0xB1, 0xF, 0xF, true));
}
__device__ __forceinline__ float qxor2(float v) {  // quad_perm [2,3,0,1]
    return __int_as_float(__builtin_amdgcn_mov_dpp(__float_as_int(v), 0x4E, 0xF, 0xF, true));
}
__device__ __forceinline__ float qrev(float v) {   // quad_perm [3,2,1,0] == xor 3
    return __int_as_float(__builtin_amdgcn_mov_dpp(__float_as_int(v), 0x1B, 0xF, 0xF, true));
}

// Raw v_exp_f32 (no pre-mul, no ocml edge-case fixup).
extern "C" __device__ float __ocml_native_exp2_f32(float);
__device__ __forceinline__ float fexp2(float x) {
#if __has_builtin(__builtin_amdgcn_exp2f)
    return __builtin_amdgcn_exp2f(x);
#else
    return __ocml_native_exp2_f32(x);
#endif
}
__device__ __forceinline__ float frcp(float x) { return __builtin_amdgcn_rcpf(x); }
__device__ __forceinline__ float4 ld4(const float* p) { return *(const float4*)p; }

// hp[k] = { h[(j+sgn*2k)&15], h[(j+sgn*(2k+1))&15] }
#define FILL_HP(hp, h)                                   \
    do {                                                 \
        hp[0].x = (h);        hp[0].y = rotf<1>(h);      \
        hp[1].x = rotf<2>(h); hp[1].y = rotf<3>(h);      \
        hp[2].x = rotf<4>(h); hp[2].y = rotf<5>(h);      \
        hp[3].x = rotf<6>(h); hp[3].y = rotf<7>(h);      \
        hp[4].x = rotf<8>(h); hp[4].y = rotf<9>(h);      \
        hp[5].x = rotf<10>(h); hp[5].y = rotf<11>(h);    \
        hp[6].x = rotf<12>(h); hp[6].y = rotf<13>(h);    \
        hp[7].x = rotf<14>(h); hp[7].y = rotf<15>(h);    \
    } while (0)

// 16-dot, depth 5 from hp-ready: 2+2 fma chains + pk-add tree + hadd.
__device__ __forceinline__ float dot8p(const v2f* __restrict__ w, const v2f* hp, float start) {
    v2f c0 = __builtin_elementwise_fma(w[0], hp[0], (v2f){start, 0.0f});
    c0 = __builtin_elementwise_fma(w[1], hp[1], c0);
    v2f c1 = __builtin_elementwise_fma(w[3], hp[3], w[2] * hp[2]);
    v2f c2 = __builtin_elementwise_fma(w[5], hp[5], w[4] * hp[4]);
    v2f c3 = __builtin_elementwise_fma(w[7], hp[7], w[6] * hp[6]);
    v2f s = (c0 + c1) + (c2 + c3);
    return s.x + s.y;
}

// 128 blocks x 64 threads. Each wave: 4 batch elements x 16 lanes.
__global__ __launch_bounds__(64, 1) void rnn_kernel(
    const float* __restrict__ gt,
    const float* __restrict__ eWih, const float* __restrict__ eWhh,
    const float* __restrict__ ebih, const float* __restrict__ ebhh,
    const float* __restrict__ dWih, const float* __restrict__ dWhh,
    const float* __restrict__ dbih, const float* __restrict__ dbhh,
    const float* __restrict__ oW,  const float* __restrict__ ob,
    float* __restrict__ outs)                 // [NB][S_LEN][4] logit scratch
{
    const int lane = threadIdx.x;
    const int j    = lane & 15;
    const int q    = j & 3;
    const int b    = blockIdx.x * 4 + (lane >> 4);

    // DPP row_ror direction probe (direction-agnostic weight indexing).
    int probe = __builtin_amdgcn_mov_dpp(j, 0x121, 0xF, 0xF, true);
    const int sgn = (probe == ((j + 1) & 15)) ? 1 : -1;

    const float* gb = gt + (size_t)b * (NV * S_LEN);

    // ---------------- encoder weights (paired, rotated, exp2-prescaled) ----------------
    v2f ewr[8], ewz[8], ewn[8];
#pragma unroll
    for (int p = 0; p < 8; ++p) {
        int k0 = (j + sgn * (2 * p)) & 15;
        int k1 = (j + sgn * (2 * p + 1)) & 15;
        ewr[p] = (v2f){NL * eWhh[(0 * NH + j) * NH + k0], NL * eWhh[(0 * NH + j) * NH + k1]};
        ewz[p] = (v2f){NL * eWhh[(1 * NH + j) * NH + k0], NL * eWhh[(1 * NH + j) * NH + k1]};
        ewn[p] = (v2f){S2L * eWhh[(2 * NH + j) * NH + k0], S2L * eWhh[(2 * NH + j) * NH + k1]};
    }
    float exr[NV], exz[NV], exn[NV];
#pragma unroll
    for (int v = 0; v < NV; ++v) {
        exr[v] = NL  * eWih[(0 * NH + j) * NV + v];
        exz[v] = NL  * eWih[(1 * NH + j) * NV + v];
        exn[v] = S2L * eWih[(2 * NH + j) * NV + v];
    }
    const float c_er  = NL  * (ebih[j] + ebhh[j]);
    const float c_ez  = NL  * (ebih[NH + j] + ebhh[NH + j]);
    const float c_ein = S2L * ebih[2 * NH + j];
    const float c_ehn = S2L * ebhh[2 * NH + j];

    float h = 0.0f;

    // estep: gate args pre-scaled so they feed v_exp_f32 directly.
    auto estep = [&](float x0, float x1, float x2, float x3) {
        float xr = fmaf(exr[0], x0, fmaf(exr[1], x1, fmaf(exr[2], x2, fmaf(exr[3], x3, c_er))));
        float xz = fmaf(exz[0], x0, fmaf(exz[1], x1, fmaf(exz[2], x2, fmaf(exz[3], x3, c_ez))));
        float xn = fmaf(exn[0], x0, fmaf(exn[1], x1, fmaf(exn[2], x2, fmaf(exn[3], x3, c_ein))));
        v2f hp[8];
        FILL_HP(hp, h);
        float ar = dot8p(ewr, hp, xr);       // = -log2e * (raw r pre-act)
        float az = dot8p(ewz, hp, xz);
        float hn = dot8p(ewn, hp, c_ehn);    // = -2log2e * (hn dot + bhh_n)
        float r  = frcp(1.0f + fexp2(ar));
        float z  = frcp(1.0f + fexp2(az));
        float t2 = fmaf(-2.0f, z, 2.0f);     // z-side, parallel to r-chain
        float tb = fmaf(z, h, z - 1.0f);
        float y  = fmaf(r, hn, xn);          // -2log2e * tanh-arg
        float w2 = frcp(1.0f + fexp2(y));
        h = fmaf(w2, t2, tb);
    };

    // ---------------- encoder loop ----------------
    {
        float4 A0 = ld4(gb + 0 * S_LEN), A1 = ld4(gb + 1 * S_LEN),
               A2 = ld4(gb + 2 * S_LEN), A3 = ld4(gb + 3 * S_LEN);
        float4 B0 = ld4(gb + 0 * S_LEN + 4), B1 = ld4(gb + 1 * S_LEN + 4),
               B2 = ld4(gb + 2 * S_LEN + 4), B3 = ld4(gb + 3 * S_LEN + 4);
        for (int t = 0; t < S_LEN; t += 8) {
            estep(A0.x, A1.x, A2.x, A3.x);
            estep(A0.y, A1.y, A2.y, A3.y);
            estep(A0.z, A1.z, A2.z, A3.z);
            estep(A0.w, A1.w, A2.w, A3.w);
            int ta = t + 8;  if (ta > S_LEN - 4) ta = S_LEN - 4;
            A0 = ld4(gb + 0 * S_LEN + ta); A1 = ld4(gb + 1 * S_LEN + ta);
            A2 = ld4(gb + 2 * S_LEN + ta); A3 = ld4(gb + 3 * S_LEN + ta);
            estep(B0.x, B1.x, B2.x, B3.x);
            estep(B0.y, B1.y, B2.y, B3.y);
            estep(B0.z, B1.z, B2.z, B3.z);
            estep(B0.w, B1.w, B2.w, B3.w);
            int tb2 = t + 12; if (tb2 > S_LEN - 4) tb2 = S_LEN - 4;
            B0 = ld4(gb + 0 * S_LEN + tb2); B1 = ld4(gb + 1 * S_LEN + tb2);
            B2 = ld4(gb + 2 * S_LEN + tb2); B3 = ld4(gb + 3 * S_LEN + tb2);
        }
    }

    // ---------------- decoder weights ----------------
    v2f dwr[8], dwz[8], dwn[8], ow2[8];
#pragma unroll
    for (int p = 0; p < 8; ++p) {
        int k0 = (j + sgn * (2 * p)) & 15;
        int k1 = (j + sgn * (2 * p + 1)) & 15;
        dwr[p] = (v2f){NL * dWhh[(0 * NH + j) * NH + k0], NL * dWhh[(0 * NH + j) * NH + k1]};
        dwz[p] = (v2f){NL * dWhh[(1 * NH + j) * NH + k0], NL * dWhh[(1 * NH + j) * NH + k1]};
        dwn[p] = (v2f){S2L * dWhh[(2 * NH + j) * NH + k0], S2L * dWhh[(2 * NH + j) * NH + k1]};
        ow2[p] = (v2f){oW[q * NH + k0], oW[q * NH + k1]};
    }
    const float sR  = NL  * (dbih[j] + dbhh[j]);             // r-dot start
    const float sZ  = NL  * (dbih[NH + j] + dbhh[NH + j]);   // z-dot start
    const float sHn = S2L * dbhh[2 * NH + j];                // hn-dot start
    const float cIn = S2L * dbih[2 * NH + j];                // inn bias (n-path const)
    // Multiplicative one-hot constants 2^{scaled K}, REGISTER order m (class = m ^ q):
    float EKr[NV], EKz[NV], EKn[NV];
#pragma unroll
    for (int m = 0; m < NV; ++m) {
        int c = m ^ q;
        EKr[m] = exp2f(NL  * dWih[(0 * NH + j) * NV + c]);
        EKz[m] = exp2f(NL  * dWih[(1 * NH + j) * NV + c]);
        EKn[m] = exp2f(S2L * dWih[(2 * NH + j) * NV + c]);
    }
    const float obq = ob[q];

    int oidx = (b << 15) + q;       // (b*S_LEN + 0)*4 + q  -- [B][S][4] layout
    const bool storer = (j < 4);    // quad 0 of each row stores out[0..3]

    // dstep: gathers h'(t-1); dots; exp2 of gate args overlaps the argmax tournament;
    // gate = rcp(fma(E, EK_class, 1)). Stores logits of step t-1.
    auto dstep = [&]() {
        v2f hp[8];
        FILL_HP(hp, h);
        float ar = dot8p(dwr, hp, sR);
        float az = dot8p(dwz, hp, sZ);
        float hn = dot8p(dwn, hp, sHn);
        float oa = dot8p(ow2, hp, obq);
        if (storer) outs[oidx] = oa;
        oidx += 4;
        float o_b = qxor1(oa);               // out[q^1]
        float o_c = qxor2(oa);               // out[q^2]
        float o_d = qrev(oa);                // out[q^3]
        bool cA = o_b > oa;  float mA = fmaxf(oa, o_b);
        bool cB = o_d > o_c; float mB = fmaxf(o_c, o_d);
        bool hi = mB > mA;
        float ekr = hi ? (cB ? EKr[3] : EKr[2]) : (cA ? EKr[1] : EKr[0]);
        float ekz = hi ? (cB ? EKz[3] : EKz[2]) : (cA ? EKz[1] : EKz[0]);
        float ekn = hi ? (cB ? EKn[3] : EKn[2]) : (cA ? EKn[1] : EKn[0]);
        float r  = frcp(fmaf(fexp2(ar), ekr, 1.0f));
        float z  = frcp(fmaf(fexp2(az), ekz, 1.0f));
        float t2 = fmaf(-2.0f, z, 2.0f);
        float tb = fmaf(z, h, z - 1.0f);
        float y  = fmaf(r, hn, cIn);
        float w2 = frcp(fmaf(fexp2(y), ekn, 1.0f));
        h = fmaf(w2, t2, tb);
    };

    // t = 0: x0 = zeros (EK factors = 1), no previous logits
    {
        v2f hp[8];
        FILL_HP(hp, h);
        float ar = dot8p(dwr, hp, sR);
        float az = dot8p(dwz, hp, sZ);
        float hn = dot8p(dwn, hp, sHn);
        float r  = frcp(1.0f + fexp2(ar));
        float z  = frcp(1.0f + fexp2(az));
        float t2 = fmaf(-2.0f, z, 2.0f);
        float tb = fmaf(z, h, z - 1.0f);
        float y  = fmaf(r, hn, cIn);
        float w2 = frcp(1.0f + fexp2(y));
        h = fmaf(w2, t2, tb);
    }
    // t = 1..8191
    for (int u = 0; u < 2047; ++u) {
        dstep(); dstep(); dstep(); dstep();
    }
    dstep(); dstep(); dstep();
    // tail: logits of final step (t = S-1)
    {
        v2f hp[8];
        FILL_HP(hp, h);
        float oa = dot8p(ow2, hp, obq);
        if (storer) outs[oidx] = oa;
    }
}

// Epilogue: NLL over all (b,t) from stored logits + gt targets; zero the scratch
// (restores the required all-zero output_batch). 4096 blocks x 1024 threads.
__global__ __launch_bounds__(1024) void loss_kernel(
    const float* __restrict__ gt, float* __restrict__ outs, float* __restrict__ loss)
{
    int tid = blockIdx.x * 1024 + threadIdx.x;   // over NB*S_LEN
    int t = tid & (S_LEN - 1);
    int b = tid >> 13;
    float4 o = *(const float4*)(outs + (size_t)tid * 4);
    const float* g = gt + (size_t)b * (NV * S_LEN) + t;
    float p0 = g[0], p1 = g[S_LEN], p2 = g[2 * S_LEN], p3 = g[3 * S_LEN];
    int tg = (p1 > p0) ? 1 : 0;  float bm = fmaxf(p0, p1);
    tg = (p2 > bm) ? 2 : tg;     bm = fmaxf(p2, bm);
    tg = (p3 > bm) ? 3 : tg;
    float vt = (tg & 1) ? ((tg & 2) ? o.w : o.y) : ((tg & 2) ? o.z : o.x);
    float mx = fmaxf(fmaxf(o.x, o.y), fmaxf(o.z, o.w));
    float ss = __expf(o.x - mx) + __expf(o.y - mx) + __expf(o.z - mx) + __expf(o.w - mx);
    float v  = (mx - vt) + __logf(ss);
    *(float4*)(outs + (size_t)tid * 4) = make_float4(0.f, 0.f, 0.f, 0.f);
    // wave reduce
#pragma unroll
    for (int d = 1; d < 64; d <<= 1) v += __shfl_xor(v, d, 64);
    __shared__ float sm[16];
    int w = threadIdx.x >> 6;
    if ((threadIdx.x & 63) == 0) sm[w] = v;
    __syncthreads();
    if (threadIdx.x < 16) {
        float s = sm[threadIdx.x];
#pragma unroll
        for (int d = 1; d < 16; d <<= 1) s += __shfl_xor(s, d, 64);
        if (threadIdx.x == 0) atomicAdd(loss, s * (1.0f / NB));
    }
}

extern "C" void kernel_launch(void* const* d_in, const int* in_sizes, int n_in,
                              void* d_out, int out_size, void* d_ws, size_t ws_size,
                              hipStream_t stream) {
    (void)in_sizes; (void)n_in; (void)d_ws; (void)ws_size; (void)out_size;
    const float* gt   = (const float*)d_in[0];
    const float* eWih = (const float*)d_in[1];
    const float* eWhh = (const float*)d_in[2];
    const float* ebih = (const float*)d_in[3];
    const float* ebhh = (const float*)d_in[4];
    const float* dWih = (const float*)d_in[5];
    const float* dWhh = (const float*)d_in[6];
    const float* dbih = (const float*)d_in[7];
    const float* dbhh = (const float*)d_in[8];
    const float* oW   = (const float*)d_in[9];
    const float* ob   = (const float*)d_in[10];

    float* out  = (float*)d_out;       // out[0] = loss
    float* outs = out + 1;             // [NB][S_LEN][4] logit scratch == output_batch region
    hipMemsetAsync(d_out, 0, sizeof(float), stream);   // zero loss only
    rnn_kernel<<<NB / 4, 64, 0, stream>>>(gt, eWih, eWhh, ebih, ebhh,
                                          dWih, dWhh, dbih, dbhh, oW, ob, outs);
    loss_kernel<<<(NB * S_LEN) / 1024, 1024, 0, stream>>>(gt, outs, out);
}